// Round 16
// baseline (292.793 us; speedup 1.0000x reference)
//
#include <hip/hip_runtime.h>

#define HF 128       // feature width (F == H == 128)
#define TILE 128     // cols per fine bucket
#define CAP2 6144    // entries per fine bucket (mean ~4096 + slack)
#define NFINE_MAX 512
#define SORT_CHUNK 2048
#define BN_EPS 1e-5f
#define SMEM_FUSED 22528   // sort: staged 8K + sbkt 4K + 4 tables 8K + s 2K; gemm32: 18432

__device__ __forceinline__ unsigned short f2bf(float f) {
    unsigned u = __float_as_uint(f);
    unsigned rounding = 0x7FFF + ((u >> 16) & 1);  // round-to-nearest-even
    return (unsigned short)((u + rounding) >> 16);
}
__device__ __forceinline__ float bf2f(unsigned short u) {
    return __uint_as_float(((unsigned)u) << 16);
}
__device__ __forceinline__ unsigned packbf(float lo, float hi) {
    return ((unsigned)f2bf(hi) << 16) | (unsigned)f2bf(lo);
}

// ---------- bucket_sort block body: 2048 edges, 8/thread in REGISTERS ----------
// smem: staged u32[2048] @0 | sbkt u16[2048] @8192 | hist @12288 | lbase @14336
//       | gbase @16384 | lofs @18432 | s @20480   (total 22528B)
__device__ __forceinline__ void bucket_sort_block(char* smem, int bid,
                                                  const int* __restrict__ row,
                                                  const int* __restrict__ col,
                                                  unsigned* __restrict__ buckets,
                                                  int* __restrict__ cursor,
                                                  int E, int nfine) {
    unsigned* staged = (unsigned*)smem;
    unsigned short* sbkt = (unsigned short*)(smem + 8192);
    int* hist  = (int*)(smem + 12288);
    int* lbase = (int*)(smem + 14336);
    int* gbase = (int*)(smem + 16384);
    int* lofs  = (int*)(smem + 18432);
    int* s     = (int*)(smem + 20480);
    int t = threadIdx.x;
    for (int i = t; i < NFINE_MAX; i += 256) { hist[i] = 0; lofs[i] = 0; }
    __syncthreads();
    int e0 = bid * SORT_CHUNK + t * 8;
    int cc[8], rr[8], pg[8];
    unsigned pk[8];
    if (e0 + 8 <= E) {
        int4 c0 = *reinterpret_cast<const int4*>(col + e0);
        int4 c1 = *reinterpret_cast<const int4*>(col + e0 + 4);
        int4 r0 = *reinterpret_cast<const int4*>(row + e0);
        int4 r1 = *reinterpret_cast<const int4*>(row + e0 + 4);
        cc[0]=c0.x; cc[1]=c0.y; cc[2]=c0.z; cc[3]=c0.w;
        cc[4]=c1.x; cc[5]=c1.y; cc[6]=c1.z; cc[7]=c1.w;
        rr[0]=r0.x; rr[1]=r0.y; rr[2]=r0.z; rr[3]=r0.w;
        rr[4]=r1.x; rr[5]=r1.y; rr[6]=r1.z; rr[7]=r1.w;
    } else {
        #pragma unroll
        for (int i = 0; i < 8; ++i) {
            int e = e0 + i;
            cc[i] = (e < E) ? col[e] : -1;
            rr[i] = (e < E) ? row[e] : 0;
        }
    }
    #pragma unroll
    for (int i = 0; i < 8; ++i) {
        if (cc[i] >= 0) {
            int b = cc[i] >> 7;
            pg[i] = b;
            pk[i] = ((unsigned)(cc[i] & 127) << 17) | (unsigned)rr[i];
            atomicAdd(&hist[b], 1);
        } else {
            pg[i] = -1;
        }
    }
    __syncthreads();
    // Blelloch exclusive scan of hist[0..512) -> lbase
    s[t] = hist[t];
    s[t + 256] = hist[t + 256];
    for (int o = 1; o < 512; o <<= 1) {
        __syncthreads();
        int idx = (t + 1) * (o << 1) - 1;
        if (idx < 512) s[idx] += s[idx - o];
    }
    __syncthreads();
    if (t == 0) s[511] = 0;
    for (int o = 256; o >= 1; o >>= 1) {
        __syncthreads();
        int idx = (t + 1) * (o << 1) - 1;
        if (idx < 512) { int tmp = s[idx - o]; s[idx - o] = s[idx]; s[idx] += tmp; }
    }
    __syncthreads();
    lbase[t] = s[t];
    lbase[t + 256] = s[t + 256];
    for (int b = t; b < nfine; b += 256) {
        int cnt = hist[b];
        gbase[b] = cnt ? atomicAdd(&cursor[b * 16], cnt) : 0;
    }
    __syncthreads();
    #pragma unroll
    for (int i = 0; i < 8; ++i) {
        if (pg[i] >= 0) {
            int pos = lbase[pg[i]] + atomicAdd(&lofs[pg[i]], 1);
            staged[pos] = pk[i];
            sbkt[pos] = (unsigned short)pg[i];
        }
    }
    __syncthreads();
    int n = min(SORT_CHUNK, E - bid * SORT_CHUNK);
    for (int i = t; i < n; i += 256) {
        int b = sbkt[i];
        int pos = gbase[b] + (i - lbase[b]);
        if (pos < CAP2) buckets[(size_t)b * CAP2 + pos] = staged[i];
    }
}

// ---------- gemm32 block body: 32-row x 128-col tile, 4x4/thread (18KB LDS) ----------
__device__ __forceinline__ void gemm_block32(char* smem, int bid,
                                             const float* __restrict__ X,
                                             const float* __restrict__ W,
                                             unsigned short* __restrict__ Y, int N) {
    float (*xst)[36] = (float(*)[36])smem;  // [128][36], 144B row stride (16B-aligned)
    int t = threadIdx.x;
    int row0 = bid * 32;
    {
        int f = t & 127;
        for (int r = (t >> 7); r < 32; r += 2) {
            int rr = row0 + r;
            xst[f][r] = (rr < N) ? X[(size_t)rr * HF + f] : 0.0f;
        }
    }
    __syncthreads();
    int cg = t & 31;
    int rg = t >> 5;
    int r0 = rg * 4;
    float acc[4][4] = {};
    const float4* Wv = reinterpret_cast<const float4*>(W);
    #pragma unroll 4
    for (int f = 0; f < HF; ++f) {
        float4 w = Wv[f * 32 + cg];
        float4 xv = *reinterpret_cast<const float4*>(&xst[f][r0]);
        float xr[4] = {xv.x, xv.y, xv.z, xv.w};
        #pragma unroll
        for (int i = 0; i < 4; ++i) {
            acc[i][0] += xr[i] * w.x;
            acc[i][1] += xr[i] * w.y;
            acc[i][2] += xr[i] * w.z;
            acc[i][3] += xr[i] * w.w;
        }
    }
    #pragma unroll
    for (int i = 0; i < 4; ++i) {
        int rr = row0 + r0 + i;
        if (rr < N) {
            ushort4 o;
            o.x = f2bf(acc[i][0]);
            o.y = f2bf(acc[i][1]);
            o.z = f2bf(acc[i][2]);
            o.w = f2bf(acc[i][3]);
            *reinterpret_cast<ushort4*>(&Y[(size_t)rr * HF + cg * 4]) = o;
        }
    }
}

// ---------- fused: bucket_sort (blocks < nsort) || gemm1 UNSCALED (rest) ----------
// Legal: buckets alias B (dead until gather1) while gemm writes A. dinv not yet
// known -> gemm writes unscaled xw; tile_place2 scales A afterward.
__global__ __launch_bounds__(256) void sort_gemm1(const int* __restrict__ row,
                                                  const int* __restrict__ col,
                                                  unsigned* __restrict__ buckets,
                                                  int* __restrict__ cursor,
                                                  int E, int nfine, int nsort,
                                                  const float* __restrict__ x,
                                                  const float* __restrict__ W1,
                                                  unsigned short* __restrict__ A,
                                                  int N) {
    __shared__ __align__(16) char smem[SMEM_FUSED];
    if (blockIdx.x < nsort)
        bucket_sort_block(smem, blockIdx.x, row, col, buckets, cursor, E, nfine);
    else
        gemm_block32(smem, blockIdx.x - nsort, x, W1, A, N);
}

// ---------- standalone gemm (conv2): 64x128 tile, BN1+ReLU on bf16 in, dinv rowscale ----------
__global__ __launch_bounds__(256) void gemm_rt(const unsigned short* __restrict__ Xh,
                                               const float* __restrict__ W,
                                               unsigned short* __restrict__ Y,
                                               const float* __restrict__ scale,
                                               const float* __restrict__ shift,
                                               const float* __restrict__ rowscale,
                                               int N) {
    __shared__ float xst[HF][68];  // 34816B
    int t = threadIdx.x;
    int row0 = blockIdx.x * 64;
    {
        int f = t & 127;
        float sc = scale[f];
        float sh = shift[f];
        for (int r = (t >> 7); r < 64; r += 2) {
            int rr = row0 + r;
            float v = 0.0f;
            if (rr < N) {
                v = bf2f(Xh[(size_t)rr * HF + f]);
                v = fmaxf(v * sc + sh, 0.0f);
            }
            xst[f][r] = v;
        }
    }
    __syncthreads();
    int cg = t & 31;
    int rg = t >> 5;
    int r0 = rg * 8;
    float acc[8][4] = {};
    const float4* Wv = reinterpret_cast<const float4*>(W);
    #pragma unroll 2
    for (int f = 0; f < HF; ++f) {
        float4 w = Wv[f * 32 + cg];
        float4 x0 = *reinterpret_cast<const float4*>(&xst[f][r0]);
        float4 x1 = *reinterpret_cast<const float4*>(&xst[f][r0 + 4]);
        float xr[8] = {x0.x, x0.y, x0.z, x0.w, x1.x, x1.y, x1.z, x1.w};
        #pragma unroll
        for (int i = 0; i < 8; ++i) {
            acc[i][0] += xr[i] * w.x;
            acc[i][1] += xr[i] * w.y;
            acc[i][2] += xr[i] * w.z;
            acc[i][3] += xr[i] * w.w;
        }
    }
    #pragma unroll
    for (int i = 0; i < 8; ++i) {
        int rr = row0 + r0 + i;
        if (rr < N) {
            float rs = rowscale[rr];
            ushort4 o;
            o.x = f2bf(acc[i][0] * rs);
            o.y = f2bf(acc[i][1] * rs);
            o.z = f2bf(acc[i][2] * rs);
            o.w = f2bf(acc[i][3] * rs);
            *reinterpret_cast<ushort4*>(&Y[(size_t)rr * HF + cg * 4]) = o;
        }
    }
}

// ---------- fused per-bucket CSR place + A-row scaling (+graph_bounds, +rowptr[N]) ----------
__global__ __launch_bounds__(256) void tile_place2(const unsigned* __restrict__ buckets,
                                                   const int* __restrict__ cursor,
                                                   int* __restrict__ rowptr,
                                                   float* __restrict__ dinv,
                                                   int* __restrict__ srow,
                                                   unsigned short* __restrict__ A,
                                                   const int* __restrict__ batch,
                                                   int* __restrict__ gstart,
                                                   int N, int NG, int nfine) {
    int b = blockIdx.x;
    int t = threadIdx.x;
    if (b < 2 && t < 129) {
        int g = b * 129 + t;
        if (g <= NG) {
            int lo = 0, hi = N;
            while (lo < hi) {
                int mid = (lo + hi) >> 1;
                if (batch[mid] < g) lo = mid + 1; else hi = mid;
            }
            gstart[g] = lo;
        }
    }
    __shared__ int h[TILE], loc[TILE], cur[TILE];
    __shared__ float dloc[TILE];
    __shared__ int red[256];
    __shared__ int stage[CAP2];
    int part = 0;
    for (int i = t; i < b; i += 256) part += min(cursor[i * 16], CAP2);
    red[t] = part;
    if (t < TILE) h[t] = 0;
    __syncthreads();
    for (int o = 128; o > 0; o >>= 1) {
        if (t < o) red[t] += red[t + o];
        __syncthreads();
    }
    int base = red[0];
    int sz = min(cursor[b * 16], CAP2);
    const unsigned* bk = buckets + (size_t)b * CAP2;
    for (int i = t; i < sz; i += 256) atomicAdd(&h[bk[i] >> 17], 1);
    __syncthreads();
    if (t < TILE) loc[t] = h[t];
    __syncthreads();
    for (int o = 1; o < TILE; o <<= 1) {
        int v = (t < TILE && t >= o) ? loc[t - o] : 0;
        __syncthreads();
        if (t < TILE) loc[t] += v;
        __syncthreads();
    }
    int c0 = b * TILE;
    int ncols = min(TILE, N - c0);
    if (t < TILE) {
        int c = c0 + t;
        int excl = loc[t] - h[t];
        float dc = rsqrtf((float)h[t] + 1.0f);
        if (c < N) {
            rowptr[c] = base + excl;
            dinv[c] = dc;
        }
        dloc[t] = dc;
        cur[t] = excl;
    }
    if (b == nfine - 1 && t == 0) rowptr[N] = base + sz;
    __syncthreads();
    for (int i = t; i < sz; i += 256) {
        unsigned p = bk[i];
        int pos = atomicAdd(&cur[p >> 17], 1);
        if (pos < CAP2) stage[pos] = (int)(p & 0x1FFFFu);
    }
    __syncthreads();
    for (int i = t; i < sz; i += 256) srow[base + i] = stage[i];
    // fold of scale_rows: scale this block's 128 A-rows by dinv (bf16 in-place)
    const unsigned M = 0xffff0000u;
    for (int i = t; i < ncols * 16; i += 256) {
        int nl = i >> 4, j = i & 15;
        float dc = dloc[nl];
        unsigned short* ap = A + (size_t)(c0 + nl) * HF + j * 8;
        uint4 u = *reinterpret_cast<const uint4*>(ap);
        uint4 o;
        o.x = packbf(__uint_as_float(u.x << 16) * dc, __uint_as_float(u.x & M) * dc);
        o.y = packbf(__uint_as_float(u.y << 16) * dc, __uint_as_float(u.y & M) * dc);
        o.z = packbf(__uint_as_float(u.z << 16) * dc, __uint_as_float(u.z & M) * dc);
        o.w = packbf(__uint_as_float(u.w << 16) * dc, __uint_as_float(u.w & M) * dc);
        *reinterpret_cast<uint4*>(ap) = o;
    }
}

// ---------- gather-side conv (bf16 out) + fused BN partial stats ----------
__global__ __launch_bounds__(256) void gather_conv(const int* __restrict__ rowptr,
                                                   const int* __restrict__ srow,
                                                   const float* __restrict__ dinv,
                                                   const unsigned short* __restrict__ XW,
                                                   const float* __restrict__ b,
                                                   unsigned short* __restrict__ OUT,
                                                   float* __restrict__ psum,
                                                   float* __restrict__ psq, int N) {
    int blk = blockIdx.x;
    int c = blk * 16 + (threadIdx.x >> 4);
    int j = threadIdx.x & 15;  // 8 features per lane
    bool valid = (c < N);
    const unsigned M = 0xffff0000u;
    float o[8];
    if (valid) {
        int e = rowptr[c], end = rowptr[c + 1];
        float acc[8] = {0.f, 0.f, 0.f, 0.f, 0.f, 0.f, 0.f, 0.f};
        for (; e + 3 < end; e += 4) {
            int r0 = srow[e], r1 = srow[e + 1], r2 = srow[e + 2], r3 = srow[e + 3];
            uint4 u0 = *reinterpret_cast<const uint4*>(XW + (size_t)r0 * HF + j * 8);
            uint4 u1 = *reinterpret_cast<const uint4*>(XW + (size_t)r1 * HF + j * 8);
            uint4 u2 = *reinterpret_cast<const uint4*>(XW + (size_t)r2 * HF + j * 8);
            uint4 u3 = *reinterpret_cast<const uint4*>(XW + (size_t)r3 * HF + j * 8);
            acc[0] += (__uint_as_float(u0.x << 16) + __uint_as_float(u1.x << 16))
                    + (__uint_as_float(u2.x << 16) + __uint_as_float(u3.x << 16));
            acc[1] += (__uint_as_float(u0.x & M) + __uint_as_float(u1.x & M))
                    + (__uint_as_float(u2.x & M) + __uint_as_float(u3.x & M));
            acc[2] += (__uint_as_float(u0.y << 16) + __uint_as_float(u1.y << 16))
                    + (__uint_as_float(u2.y << 16) + __uint_as_float(u3.y << 16));
            acc[3] += (__uint_as_float(u0.y & M) + __uint_as_float(u1.y & M))
                    + (__uint_as_float(u2.y & M) + __uint_as_float(u3.y & M));
            acc[4] += (__uint_as_float(u0.z << 16) + __uint_as_float(u1.z << 16))
                    + (__uint_as_float(u2.z << 16) + __uint_as_float(u3.z << 16));
            acc[5] += (__uint_as_float(u0.z & M) + __uint_as_float(u1.z & M))
                    + (__uint_as_float(u2.z & M) + __uint_as_float(u3.z & M));
            acc[6] += (__uint_as_float(u0.w << 16) + __uint_as_float(u1.w << 16))
                    + (__uint_as_float(u2.w << 16) + __uint_as_float(u3.w << 16));
            acc[7] += (__uint_as_float(u0.w & M) + __uint_as_float(u1.w & M))
                    + (__uint_as_float(u2.w & M) + __uint_as_float(u3.w & M));
        }
        for (; e < end; ++e) {
            int r0 = srow[e];
            uint4 u0 = *reinterpret_cast<const uint4*>(XW + (size_t)r0 * HF + j * 8);
            acc[0] += __uint_as_float(u0.x << 16);
            acc[1] += __uint_as_float(u0.x & M);
            acc[2] += __uint_as_float(u0.y << 16);
            acc[3] += __uint_as_float(u0.y & M);
            acc[4] += __uint_as_float(u0.z << 16);
            acc[5] += __uint_as_float(u0.z & M);
            acc[6] += __uint_as_float(u0.w << 16);
            acc[7] += __uint_as_float(u0.w & M);
        }
        float dc = dinv[c];
        uint4 xv = *reinterpret_cast<const uint4*>(XW + (size_t)c * HF + j * 8);
        acc[0] += __uint_as_float(xv.x << 16);
        acc[1] += __uint_as_float(xv.x & M);
        acc[2] += __uint_as_float(xv.y << 16);
        acc[3] += __uint_as_float(xv.y & M);
        acc[4] += __uint_as_float(xv.z << 16);
        acc[5] += __uint_as_float(xv.z & M);
        acc[6] += __uint_as_float(xv.w << 16);
        acc[7] += __uint_as_float(xv.w & M);
        float4 b0 = *reinterpret_cast<const float4*>(b + j * 8);
        float4 b1 = *reinterpret_cast<const float4*>(b + j * 8 + 4);
        o[0] = dc * acc[0] + b0.x;
        o[1] = dc * acc[1] + b0.y;
        o[2] = dc * acc[2] + b0.z;
        o[3] = dc * acc[3] + b0.w;
        o[4] = dc * acc[4] + b1.x;
        o[5] = dc * acc[5] + b1.y;
        o[6] = dc * acc[6] + b1.z;
        o[7] = dc * acc[7] + b1.w;
        uint4 ov;
        ov.x = packbf(o[0], o[1]);
        ov.y = packbf(o[2], o[3]);
        ov.z = packbf(o[4], o[5]);
        ov.w = packbf(o[6], o[7]);
        *reinterpret_cast<uint4*>(OUT + (size_t)c * HF + j * 8) = ov;
    } else {
        #pragma unroll
        for (int k = 0; k < 8; ++k) o[k] = 0.f;
    }
    __shared__ float sval[16][HF + 4];
    int r = threadIdx.x >> 4;
    *reinterpret_cast<float4*>(&sval[r][j * 8]) = make_float4(o[0], o[1], o[2], o[3]);
    *reinterpret_cast<float4*>(&sval[r][j * 8 + 4]) = make_float4(o[4], o[5], o[6], o[7]);
    __syncthreads();
    if (threadIdx.x < HF) {
        float s = 0.f, sq = 0.f;
        #pragma unroll
        for (int rr = 0; rr < 16; ++rr) {
            float v = sval[rr][threadIdx.x];
            s += v;
            sq += v * v;
        }
        psum[(size_t)blk * HF + threadIdx.x] = s;
        psq[(size_t)blk * HF + threadIdx.x] = sq;
    }
}

// ---------- BN reduce (partials -> scale/shift) ----------
__global__ __launch_bounds__(256) void bn_reduce(const float* __restrict__ psum,
                                                 const float* __restrict__ psq,
                                                 const float* __restrict__ gamma,
                                                 const float* __restrict__ beta,
                                                 float* __restrict__ scale,
                                                 float* __restrict__ shift,
                                                 int nblk, int N) {
    int f = blockIdx.x;
    int t = threadIdx.x;
    float s = 0.f, sq = 0.f;
    for (int i = t; i < nblk; i += 256) {
        s += psum[(size_t)i * HF + f];
        sq += psq[(size_t)i * HF + f];
    }
    __shared__ float ls[256], lq[256];
    ls[t] = s; lq[t] = sq;
    __syncthreads();
    for (int o = 128; o > 0; o >>= 1) {
        if (t < o) { ls[t] += ls[t + o]; lq[t] += lq[t + o]; }
        __syncthreads();
    }
    if (t == 0) {
        float invn = 1.0f / (float)N;
        float mu = ls[0] * invn;
        float var = lq[0] * invn - mu * mu;
        float sc = gamma[f] * rsqrtf(var + BN_EPS);
        scale[f] = sc;
        shift[f] = beta[f] - mu * sc;
    }
}

// ---------- fused BN2+ReLU + mean/max/sum pool + classifier (bf16 B) ----------
__global__ __launch_bounds__(256) void pool_classify(const unsigned short* __restrict__ Bh,
                                                     const int* __restrict__ gstart,
                                                     const float* __restrict__ scale,
                                                     const float* __restrict__ shift,
                                                     const float* __restrict__ Wc,
                                                     const float* __restrict__ bc,
                                                     float* __restrict__ out) {
    int g = blockIdx.x;
    int t = threadIdx.x & 127;
    int half = threadIdx.x >> 7;
    int s0 = gstart[g], s1 = gstart[g + 1];
    float sc = scale[t], sh = shift[t];
    float sum = 0.f, mx = 0.f;  // 0-init == empty-graph guard
    for (int n = s0 + half; n < s1; n += 2) {
        float v = fmaxf(bf2f(Bh[(size_t)n * HF + t]) * sc + sh, 0.0f);
        sum += v;
        mx = fmaxf(mx, v);
    }
    __shared__ float shsum[2][HF], shmax[2][HF];
    __shared__ float red[3][HF];
    shsum[half][t] = sum;
    shmax[half][t] = mx;
    __syncthreads();
    if (half == 0) {
        sum += shsum[1][t];
        mx = fmaxf(mx, shmax[1][t]);
        float cntf = (float)(s1 - s0);
        float mean = sum / fmaxf(cntf, 1.0f);
        red[0][t] = mean * Wc[t * 3 + 0] + mx * Wc[(HF + t) * 3 + 0] + sum * Wc[(2 * HF + t) * 3 + 0];
        red[1][t] = mean * Wc[t * 3 + 1] + mx * Wc[(HF + t) * 3 + 1] + sum * Wc[(2 * HF + t) * 3 + 1];
        red[2][t] = mean * Wc[t * 3 + 2] + mx * Wc[(HF + t) * 3 + 2] + sum * Wc[(2 * HF + t) * 3 + 2];
    }
    __syncthreads();
    for (int o = 64; o > 0; o >>= 1) {
        if (half == 0 && t < o) {
            red[0][t] += red[0][t + o];
            red[1][t] += red[1][t + o];
            red[2][t] += red[2][t + o];
        }
        __syncthreads();
    }
    if (threadIdx.x < 3) out[g * 3 + threadIdx.x] = red[threadIdx.x][0] + bc[threadIdx.x];
}

extern "C" void kernel_launch(void* const* d_in, const int* in_sizes, int n_in,
                              void* d_out, int out_size, void* d_ws, size_t ws_size,
                              hipStream_t stream) {
    const float* x    = (const float*)d_in[0];
    const int*   ei   = (const int*)d_in[1];
    const int*   batch= (const int*)d_in[2];
    const float* W1   = (const float*)d_in[3];
    const float* b1   = (const float*)d_in[4];
    const float* g1   = (const float*)d_in[5];
    const float* be1  = (const float*)d_in[6];
    const float* W2   = (const float*)d_in[7];
    const float* b2   = (const float*)d_in[8];
    const float* g2   = (const float*)d_in[9];
    const float* be2  = (const float*)d_in[10];
    const float* Wc   = (const float*)d_in[11];
    const float* bc   = (const float*)d_in[12];
    float* out = (float*)d_out;

    const int N = in_sizes[0] / HF;
    const int E = in_sizes[1] / 2;
    const int NG = 256;
    const int* row = ei;
    const int* col = ei + E;
    const int total = N * HF;
    const int nfine = (N + TILE - 1) / TILE;  // <= 512
    const int nblkGa = (N + 15) / 16;

    // workspace carve-up (256B aligned); total ~35.8MB (known-good <= 45.2MB)
    char* w = (char*)d_ws;
    size_t off = 0;
    auto alloc = [&](size_t bytes) -> void* {
        void* p = w + off;
        off += (bytes + 255) & ~(size_t)255;
        return p;
    };
    int*            cursor    = (int*)alloc((size_t)nfine * 16 * 4);
    float*          dinv      = (float*)alloc((size_t)N * 4);
    int*            rowptr    = (int*)alloc(((size_t)N + 1) * 4);
    int*            gstart    = (int*)alloc((NG + 1) * 4);
    int*            srow      = (int*)alloc((size_t)E * 4);
    float*          psum      = (float*)alloc((size_t)nblkGa * HF * 4);
    float*          psq       = (float*)alloc((size_t)nblkGa * HF * 4);
    float*          scale     = (float*)alloc(HF * 4);
    float*          shift     = (float*)alloc(HF * 4);
    unsigned short* A         = (unsigned short*)alloc((size_t)total * 2);  // xw (bf16)
    unsigned short* B         = (unsigned short*)alloc((size_t)total * 2);  // conv out (bf16)
    // buckets (9.6MB) alias B (12.8MB): B dead until gather1 -> gemm1 runs
    // concurrently with bucket_sort (gemm writes A only).
    unsigned*       buckets   = (unsigned*)B;

    const int T256 = 256;
    int gridGemm64 = (N + 63) / 64;
    int gridGemm32 = (N + 31) / 32;
    int nsort      = (E + SORT_CHUNK - 1) / SORT_CHUNK;

    // --- fused CSR-sort || gemm1 (unscaled) ---
    hipMemsetAsync(cursor, 0, (size_t)nfine * 16 * 4, stream);
    sort_gemm1<<<nsort + gridGemm32, T256, 0, stream>>>(row, col, buckets, cursor,
                                                        E, nfine, nsort, x, W1, A, N);
    // CSR place + dinv + gstart + A-row scaling
    tile_place2<<<nfine, T256, 0, stream>>>(buckets, cursor, rowptr, dinv, srow, A,
                                            batch, gstart, N, NG, nfine);

    // --- conv1 gather (+stats) ---
    gather_conv<<<nblkGa, T256, 0, stream>>>(rowptr, srow, dinv, A, b1, B, psum, psq, N);
    bn_reduce<<<HF, 256, 0, stream>>>(psum, psq, g1, be1, scale, shift, nblkGa, N);

    // --- conv2 ---
    gemm_rt<<<gridGemm64, T256, 0, stream>>>(B, W2, A, scale, shift, dinv, N);
    gather_conv<<<nblkGa, T256, 0, stream>>>(rowptr, srow, dinv, A, b2, B, psum, psq, N);
    bn_reduce<<<HF, 256, 0, stream>>>(psum, psq, g2, be2, scale, shift, nblkGa, N);

    // --- fused BN2+ReLU + pooling + classifier ---
    pool_classify<<<NG, 256, 0, stream>>>(B, gstart, scale, shift, Wc, bc, out);
}

// Round 17
// 281.419 us; speedup vs baseline: 1.0404x; 1.0404x over previous
//
#include <hip/hip_runtime.h>

#define HF 128       // feature width (F == H == 128)
#define TILE 128     // cols per fine bucket
#define CAP2 6144    // entries per fine bucket (mean ~4096 + slack)
#define NFINE_MAX 512
#define SORT_CHUNK 4096
#define BN_EPS 1e-5f
#define SMEM_BYTES 34816  // sort layout == gemm xst[128][68] floats

__device__ __forceinline__ unsigned short f2bf(float f) {
    unsigned u = __float_as_uint(f);
    unsigned rounding = 0x7FFF + ((u >> 16) & 1);  // round-to-nearest-even
    return (unsigned short)((u + rounding) >> 16);
}
__device__ __forceinline__ float bf2f(unsigned short u) {
    return __uint_as_float(((unsigned)u) << 16);
}
__device__ __forceinline__ unsigned packbf(float lo, float hi) {
    return ((unsigned)f2bf(hi) << 16) | (unsigned)f2bf(lo);
}

// ---------- bucket_sort block body (4096 edges, two-pass; LDS laid out in smem) ----------
// smem: staged u32[4096] @0 | sbkt u16[4096] @16384 | hist @24576 | lbase @26624
//       | gbase @28672 | lofs @30720 | s @32768  (total 34816B)
__device__ __forceinline__ void bucket_sort_block(char* smem, int bid,
                                                  const int* __restrict__ row,
                                                  const int* __restrict__ col,
                                                  unsigned* __restrict__ buckets,
                                                  int* __restrict__ cursor,
                                                  int E, int nfine) {
    unsigned* staged = (unsigned*)smem;                      // 16KB
    unsigned short* sbkt = (unsigned short*)(smem + 16384);  // 8KB
    int* hist  = (int*)(smem + 24576);
    int* lbase = (int*)(smem + 26624);
    int* gbase = (int*)(smem + 28672);
    int* lofs  = (int*)(smem + 30720);
    int* s     = (int*)(smem + 32768);
    int t = threadIdx.x;
    for (int i = t; i < NFINE_MAX; i += 256) { hist[i] = 0; lofs[i] = 0; }
    __syncthreads();
    int e0 = bid * SORT_CHUNK;
    int n = min(SORT_CHUNK, E - e0);
    for (int i = t; i < n; i += 256) {
        int c = col[e0 + i];
        atomicAdd(&hist[c >> 7], 1);
    }
    __syncthreads();
    s[t] = hist[t];
    s[t + 256] = hist[t + 256];
    for (int o = 1; o < 512; o <<= 1) {
        __syncthreads();
        int idx = (t + 1) * (o << 1) - 1;
        if (idx < 512) s[idx] += s[idx - o];
    }
    __syncthreads();
    if (t == 0) s[511] = 0;
    for (int o = 256; o >= 1; o >>= 1) {
        __syncthreads();
        int idx = (t + 1) * (o << 1) - 1;
        if (idx < 512) { int tmp = s[idx - o]; s[idx - o] = s[idx]; s[idx] += tmp; }
    }
    __syncthreads();
    lbase[t] = s[t];
    lbase[t + 256] = s[t + 256];
    for (int b = t; b < nfine; b += 256) {
        int cnt = hist[b];
        gbase[b] = cnt ? atomicAdd(&cursor[b * 16], cnt) : 0;
    }
    __syncthreads();
    for (int i = t; i < n; i += 256) {
        int c = col[e0 + i];
        int r = row[e0 + i];
        int b = c >> 7;
        int pos = lbase[b] + atomicAdd(&lofs[b], 1);
        staged[pos] = ((unsigned)(c & 127) << 17) | (unsigned)r;
        sbkt[pos] = (unsigned short)b;
    }
    __syncthreads();
    for (int i = t; i < n; i += 256) {
        int b = sbkt[i];
        int pos = gbase[b] + (i - lbase[b]);
        if (pos < CAP2) buckets[(size_t)b * CAP2 + pos] = staged[i];
    }
}

// ---------- gemm block body: 64x128 tile, 8x4/thread (unscaled, f32 in, bf16 out) ----------
__device__ __forceinline__ void gemm_block64(char* smem, int bid,
                                             const float* __restrict__ X,
                                             const float* __restrict__ W,
                                             unsigned short* __restrict__ Y, int N) {
    float (*xst)[68] = (float(*)[68])smem;  // [128][68], 272B row stride
    int t = threadIdx.x;
    int row0 = bid * 64;
    {
        int f = t & 127;
        for (int r = (t >> 7); r < 64; r += 2) {
            int rr = row0 + r;
            xst[f][r] = (rr < N) ? X[(size_t)rr * HF + f] : 0.0f;
        }
    }
    __syncthreads();
    int cg = t & 31;
    int rg = t >> 5;
    int r0 = rg * 8;
    float acc[8][4] = {};
    const float4* Wv = reinterpret_cast<const float4*>(W);
    #pragma unroll 2
    for (int f = 0; f < HF; ++f) {
        float4 w = Wv[f * 32 + cg];
        float4 x0 = *reinterpret_cast<const float4*>(&xst[f][r0]);
        float4 x1 = *reinterpret_cast<const float4*>(&xst[f][r0 + 4]);
        float xr[8] = {x0.x, x0.y, x0.z, x0.w, x1.x, x1.y, x1.z, x1.w};
        #pragma unroll
        for (int i = 0; i < 8; ++i) {
            acc[i][0] += xr[i] * w.x;
            acc[i][1] += xr[i] * w.y;
            acc[i][2] += xr[i] * w.z;
            acc[i][3] += xr[i] * w.w;
        }
    }
    #pragma unroll
    for (int i = 0; i < 8; ++i) {
        int rr = row0 + r0 + i;
        if (rr < N) {
            ushort4 o;
            o.x = f2bf(acc[i][0]);
            o.y = f2bf(acc[i][1]);
            o.z = f2bf(acc[i][2]);
            o.w = f2bf(acc[i][3]);
            *reinterpret_cast<ushort4*>(&Y[(size_t)rr * HF + cg * 4]) = o;
        }
    }
}

// ---------- fused: bucket_sort (blocks < nsort) || gemm1 UNSCALED (rest) ----------
// Legal: buckets alias B (dead until gather1) while gemm writes A. dinv not yet
// known -> gemm writes unscaled xw; tile_place2 scales A afterward.
__global__ __launch_bounds__(256) void sort_gemm1(const int* __restrict__ row,
                                                  const int* __restrict__ col,
                                                  unsigned* __restrict__ buckets,
                                                  int* __restrict__ cursor,
                                                  int E, int nfine, int nsort,
                                                  const float* __restrict__ x,
                                                  const float* __restrict__ W1,
                                                  unsigned short* __restrict__ A,
                                                  int N) {
    __shared__ __align__(16) char smem[SMEM_BYTES];
    if (blockIdx.x < nsort)
        bucket_sort_block(smem, blockIdx.x, row, col, buckets, cursor, E, nfine);
    else
        gemm_block64(smem, blockIdx.x - nsort, x, W1, A, N);
}

// ---------- standalone gemm (conv2): 64x128 tile, BN1+ReLU on bf16 in, dinv rowscale ----------
__global__ __launch_bounds__(256) void gemm_rt(const unsigned short* __restrict__ Xh,
                                               const float* __restrict__ W,
                                               unsigned short* __restrict__ Y,
                                               const float* __restrict__ scale,
                                               const float* __restrict__ shift,
                                               const float* __restrict__ rowscale,
                                               int N) {
    __shared__ float xst[HF][68];  // 34816B
    int t = threadIdx.x;
    int row0 = blockIdx.x * 64;
    {
        int f = t & 127;
        float sc = scale[f];
        float sh = shift[f];
        for (int r = (t >> 7); r < 64; r += 2) {
            int rr = row0 + r;
            float v = 0.0f;
            if (rr < N) {
                v = bf2f(Xh[(size_t)rr * HF + f]);
                v = fmaxf(v * sc + sh, 0.0f);
            }
            xst[f][r] = v;
        }
    }
    __syncthreads();
    int cg = t & 31;
    int rg = t >> 5;
    int r0 = rg * 8;
    float acc[8][4] = {};
    const float4* Wv = reinterpret_cast<const float4*>(W);
    #pragma unroll 2
    for (int f = 0; f < HF; ++f) {
        float4 w = Wv[f * 32 + cg];
        float4 x0 = *reinterpret_cast<const float4*>(&xst[f][r0]);
        float4 x1 = *reinterpret_cast<const float4*>(&xst[f][r0 + 4]);
        float xr[8] = {x0.x, x0.y, x0.z, x0.w, x1.x, x1.y, x1.z, x1.w};
        #pragma unroll
        for (int i = 0; i < 8; ++i) {
            acc[i][0] += xr[i] * w.x;
            acc[i][1] += xr[i] * w.y;
            acc[i][2] += xr[i] * w.z;
            acc[i][3] += xr[i] * w.w;
        }
    }
    #pragma unroll
    for (int i = 0; i < 8; ++i) {
        int rr = row0 + r0 + i;
        if (rr < N) {
            float rs = rowscale[rr];
            ushort4 o;
            o.x = f2bf(acc[i][0] * rs);
            o.y = f2bf(acc[i][1] * rs);
            o.z = f2bf(acc[i][2] * rs);
            o.w = f2bf(acc[i][3] * rs);
            *reinterpret_cast<ushort4*>(&Y[(size_t)rr * HF + cg * 4]) = o;
        }
    }
}

// ---------- fused per-bucket CSR place + A-row scaling (+graph_bounds, +rowptr[N]) ----------
__global__ __launch_bounds__(256) void tile_place2(const unsigned* __restrict__ buckets,
                                                   const int* __restrict__ cursor,
                                                   int* __restrict__ rowptr,
                                                   float* __restrict__ dinv,
                                                   int* __restrict__ srow,
                                                   unsigned short* __restrict__ A,
                                                   const int* __restrict__ batch,
                                                   int* __restrict__ gstart,
                                                   int N, int NG, int nfine) {
    int b = blockIdx.x;
    int t = threadIdx.x;
    if (b < 2 && t < 129) {
        int g = b * 129 + t;
        if (g <= NG) {
            int lo = 0, hi = N;
            while (lo < hi) {
                int mid = (lo + hi) >> 1;
                if (batch[mid] < g) lo = mid + 1; else hi = mid;
            }
            gstart[g] = lo;
        }
    }
    __shared__ int h[TILE], loc[TILE], cur[TILE];
    __shared__ float dloc[TILE];
    __shared__ int red[256];
    __shared__ int stage[CAP2];
    int part = 0;
    for (int i = t; i < b; i += 256) part += min(cursor[i * 16], CAP2);
    red[t] = part;
    if (t < TILE) h[t] = 0;
    __syncthreads();
    for (int o = 128; o > 0; o >>= 1) {
        if (t < o) red[t] += red[t + o];
        __syncthreads();
    }
    int base = red[0];
    int sz = min(cursor[b * 16], CAP2);
    const unsigned* bk = buckets + (size_t)b * CAP2;
    for (int i = t; i < sz; i += 256) atomicAdd(&h[bk[i] >> 17], 1);
    __syncthreads();
    if (t < TILE) loc[t] = h[t];
    __syncthreads();
    for (int o = 1; o < TILE; o <<= 1) {
        int v = (t < TILE && t >= o) ? loc[t - o] : 0;
        __syncthreads();
        if (t < TILE) loc[t] += v;
        __syncthreads();
    }
    int c0 = b * TILE;
    int ncols = min(TILE, N - c0);
    if (t < TILE) {
        int c = c0 + t;
        int excl = loc[t] - h[t];
        float dc = rsqrtf((float)h[t] + 1.0f);
        if (c < N) {
            rowptr[c] = base + excl;
            dinv[c] = dc;
        }
        dloc[t] = dc;
        cur[t] = excl;
    }
    if (b == nfine - 1 && t == 0) rowptr[N] = base + sz;
    __syncthreads();
    for (int i = t; i < sz; i += 256) {
        unsigned p = bk[i];
        int pos = atomicAdd(&cur[p >> 17], 1);
        if (pos < CAP2) stage[pos] = (int)(p & 0x1FFFFu);
    }
    __syncthreads();
    for (int i = t; i < sz; i += 256) srow[base + i] = stage[i];
    // fold of scale_rows: scale this block's 128 A-rows by dinv (bf16 in-place)
    const unsigned M = 0xffff0000u;
    for (int i = t; i < ncols * 16; i += 256) {
        int nl = i >> 4, j = i & 15;
        float dc = dloc[nl];
        unsigned short* ap = A + (size_t)(c0 + nl) * HF + j * 8;
        uint4 u = *reinterpret_cast<const uint4*>(ap);
        uint4 o;
        o.x = packbf(__uint_as_float(u.x << 16) * dc, __uint_as_float(u.x & M) * dc);
        o.y = packbf(__uint_as_float(u.y << 16) * dc, __uint_as_float(u.y & M) * dc);
        o.z = packbf(__uint_as_float(u.z << 16) * dc, __uint_as_float(u.z & M) * dc);
        o.w = packbf(__uint_as_float(u.w << 16) * dc, __uint_as_float(u.w & M) * dc);
        *reinterpret_cast<uint4*>(ap) = o;
    }
}

// ---------- gather-side conv (bf16 out) + fused BN partial stats ----------
__global__ __launch_bounds__(256) void gather_conv(const int* __restrict__ rowptr,
                                                   const int* __restrict__ srow,
                                                   const float* __restrict__ dinv,
                                                   const unsigned short* __restrict__ XW,
                                                   const float* __restrict__ b,
                                                   unsigned short* __restrict__ OUT,
                                                   float* __restrict__ psum,
                                                   float* __restrict__ psq, int N) {
    int blk = blockIdx.x;
    int c = blk * 16 + (threadIdx.x >> 4);
    int j = threadIdx.x & 15;  // 8 features per lane
    bool valid = (c < N);
    const unsigned M = 0xffff0000u;
    float o[8];
    if (valid) {
        int e = rowptr[c], end = rowptr[c + 1];
        float acc[8] = {0.f, 0.f, 0.f, 0.f, 0.f, 0.f, 0.f, 0.f};
        for (; e + 3 < end; e += 4) {
            int r0 = srow[e], r1 = srow[e + 1], r2 = srow[e + 2], r3 = srow[e + 3];
            uint4 u0 = *reinterpret_cast<const uint4*>(XW + (size_t)r0 * HF + j * 8);
            uint4 u1 = *reinterpret_cast<const uint4*>(XW + (size_t)r1 * HF + j * 8);
            uint4 u2 = *reinterpret_cast<const uint4*>(XW + (size_t)r2 * HF + j * 8);
            uint4 u3 = *reinterpret_cast<const uint4*>(XW + (size_t)r3 * HF + j * 8);
            acc[0] += (__uint_as_float(u0.x << 16) + __uint_as_float(u1.x << 16))
                    + (__uint_as_float(u2.x << 16) + __uint_as_float(u3.x << 16));
            acc[1] += (__uint_as_float(u0.x & M) + __uint_as_float(u1.x & M))
                    + (__uint_as_float(u2.x & M) + __uint_as_float(u3.x & M));
            acc[2] += (__uint_as_float(u0.y << 16) + __uint_as_float(u1.y << 16))
                    + (__uint_as_float(u2.y << 16) + __uint_as_float(u3.y << 16));
            acc[3] += (__uint_as_float(u0.y & M) + __uint_as_float(u1.y & M))
                    + (__uint_as_float(u2.y & M) + __uint_as_float(u3.y & M));
            acc[4] += (__uint_as_float(u0.z << 16) + __uint_as_float(u1.z << 16))
                    + (__uint_as_float(u2.z << 16) + __uint_as_float(u3.z << 16));
            acc[5] += (__uint_as_float(u0.z & M) + __uint_as_float(u1.z & M))
                    + (__uint_as_float(u2.z & M) + __uint_as_float(u3.z & M));
            acc[6] += (__uint_as_float(u0.w << 16) + __uint_as_float(u1.w << 16))
                    + (__uint_as_float(u2.w << 16) + __uint_as_float(u3.w << 16));
            acc[7] += (__uint_as_float(u0.w & M) + __uint_as_float(u1.w & M))
                    + (__uint_as_float(u2.w & M) + __uint_as_float(u3.w & M));
        }
        for (; e < end; ++e) {
            int r0 = srow[e];
            uint4 u0 = *reinterpret_cast<const uint4*>(XW + (size_t)r0 * HF + j * 8);
            acc[0] += __uint_as_float(u0.x << 16);
            acc[1] += __uint_as_float(u0.x & M);
            acc[2] += __uint_as_float(u0.y << 16);
            acc[3] += __uint_as_float(u0.y & M);
            acc[4] += __uint_as_float(u0.z << 16);
            acc[5] += __uint_as_float(u0.z & M);
            acc[6] += __uint_as_float(u0.w << 16);
            acc[7] += __uint_as_float(u0.w & M);
        }
        float dc = dinv[c];
        uint4 xv = *reinterpret_cast<const uint4*>(XW + (size_t)c * HF + j * 8);
        acc[0] += __uint_as_float(xv.x << 16);
        acc[1] += __uint_as_float(xv.x & M);
        acc[2] += __uint_as_float(xv.y << 16);
        acc[3] += __uint_as_float(xv.y & M);
        acc[4] += __uint_as_float(xv.z << 16);
        acc[5] += __uint_as_float(xv.z & M);
        acc[6] += __uint_as_float(xv.w << 16);
        acc[7] += __uint_as_float(xv.w & M);
        float4 b0 = *reinterpret_cast<const float4*>(b + j * 8);
        float4 b1 = *reinterpret_cast<const float4*>(b + j * 8 + 4);
        o[0] = dc * acc[0] + b0.x;
        o[1] = dc * acc[1] + b0.y;
        o[2] = dc * acc[2] + b0.z;
        o[3] = dc * acc[3] + b0.w;
        o[4] = dc * acc[4] + b1.x;
        o[5] = dc * acc[5] + b1.y;
        o[6] = dc * acc[6] + b1.z;
        o[7] = dc * acc[7] + b1.w;
        uint4 ov;
        ov.x = packbf(o[0], o[1]);
        ov.y = packbf(o[2], o[3]);
        ov.z = packbf(o[4], o[5]);
        ov.w = packbf(o[6], o[7]);
        *reinterpret_cast<uint4*>(OUT + (size_t)c * HF + j * 8) = ov;
    } else {
        #pragma unroll
        for (int k = 0; k < 8; ++k) o[k] = 0.f;
    }
    __shared__ float sval[16][HF + 4];
    int r = threadIdx.x >> 4;
    *reinterpret_cast<float4*>(&sval[r][j * 8]) = make_float4(o[0], o[1], o[2], o[3]);
    *reinterpret_cast<float4*>(&sval[r][j * 8 + 4]) = make_float4(o[4], o[5], o[6], o[7]);
    __syncthreads();
    if (threadIdx.x < HF) {
        float s = 0.f, sq = 0.f;
        #pragma unroll
        for (int rr = 0; rr < 16; ++rr) {
            float v = sval[rr][threadIdx.x];
            s += v;
            sq += v * v;
        }
        psum[(size_t)blk * HF + threadIdx.x] = s;
        psq[(size_t)blk * HF + threadIdx.x] = sq;
    }
}

// ---------- BN reduce (partials -> scale/shift) ----------
__global__ __launch_bounds__(256) void bn_reduce(const float* __restrict__ psum,
                                                 const float* __restrict__ psq,
                                                 const float* __restrict__ gamma,
                                                 const float* __restrict__ beta,
                                                 float* __restrict__ scale,
                                                 float* __restrict__ shift,
                                                 int nblk, int N) {
    int f = blockIdx.x;
    int t = threadIdx.x;
    float s = 0.f, sq = 0.f;
    for (int i = t; i < nblk; i += 256) {
        s += psum[(size_t)i * HF + f];
        sq += psq[(size_t)i * HF + f];
    }
    __shared__ float ls[256], lq[256];
    ls[t] = s; lq[t] = sq;
    __syncthreads();
    for (int o = 128; o > 0; o >>= 1) {
        if (t < o) { ls[t] += ls[t + o]; lq[t] += lq[t + o]; }
        __syncthreads();
    }
    if (t == 0) {
        float invn = 1.0f / (float)N;
        float mu = ls[0] * invn;
        float var = lq[0] * invn - mu * mu;
        float sc = gamma[f] * rsqrtf(var + BN_EPS);
        scale[f] = sc;
        shift[f] = beta[f] - mu * sc;
    }
}

// ---------- fused BN2+ReLU + mean/max/sum pool + classifier (bf16 B) ----------
__global__ __launch_bounds__(256) void pool_classify(const unsigned short* __restrict__ Bh,
                                                     const int* __restrict__ gstart,
                                                     const float* __restrict__ scale,
                                                     const float* __restrict__ shift,
                                                     const float* __restrict__ Wc,
                                                     const float* __restrict__ bc,
                                                     float* __restrict__ out) {
    int g = blockIdx.x;
    int t = threadIdx.x & 127;
    int half = threadIdx.x >> 7;
    int s0 = gstart[g], s1 = gstart[g + 1];
    float sc = scale[t], sh = shift[t];
    float sum = 0.f, mx = 0.f;  // 0-init == empty-graph guard
    for (int n = s0 + half; n < s1; n += 2) {
        float v = fmaxf(bf2f(Bh[(size_t)n * HF + t]) * sc + sh, 0.0f);
        sum += v;
        mx = fmaxf(mx, v);
    }
    __shared__ float shsum[2][HF], shmax[2][HF];
    __shared__ float red[3][HF];
    shsum[half][t] = sum;
    shmax[half][t] = mx;
    __syncthreads();
    if (half == 0) {
        sum += shsum[1][t];
        mx = fmaxf(mx, shmax[1][t]);
        float cntf = (float)(s1 - s0);
        float mean = sum / fmaxf(cntf, 1.0f);
        red[0][t] = mean * Wc[t * 3 + 0] + mx * Wc[(HF + t) * 3 + 0] + sum * Wc[(2 * HF + t) * 3 + 0];
        red[1][t] = mean * Wc[t * 3 + 1] + mx * Wc[(HF + t) * 3 + 1] + sum * Wc[(2 * HF + t) * 3 + 1];
        red[2][t] = mean * Wc[t * 3 + 2] + mx * Wc[(HF + t) * 3 + 2] + sum * Wc[(2 * HF + t) * 3 + 2];
    }
    __syncthreads();
    for (int o = 64; o > 0; o >>= 1) {
        if (half == 0 && t < o) {
            red[0][t] += red[0][t + o];
            red[1][t] += red[1][t + o];
            red[2][t] += red[2][t + o];
        }
        __syncthreads();
    }
    if (threadIdx.x < 3) out[g * 3 + threadIdx.x] = red[threadIdx.x][0] + bc[threadIdx.x];
}

extern "C" void kernel_launch(void* const* d_in, const int* in_sizes, int n_in,
                              void* d_out, int out_size, void* d_ws, size_t ws_size,
                              hipStream_t stream) {
    const float* x    = (const float*)d_in[0];
    const int*   ei   = (const int*)d_in[1];
    const int*   batch= (const int*)d_in[2];
    const float* W1   = (const float*)d_in[3];
    const float* b1   = (const float*)d_in[4];
    const float* g1   = (const float*)d_in[5];
    const float* be1  = (const float*)d_in[6];
    const float* W2   = (const float*)d_in[7];
    const float* b2   = (const float*)d_in[8];
    const float* g2   = (const float*)d_in[9];
    const float* be2  = (const float*)d_in[10];
    const float* Wc   = (const float*)d_in[11];
    const float* bc   = (const float*)d_in[12];
    float* out = (float*)d_out;

    const int N = in_sizes[0] / HF;
    const int E = in_sizes[1] / 2;
    const int NG = 256;
    const int* row = ei;
    const int* col = ei + E;
    const int total = N * HF;
    const int nfine = (N + TILE - 1) / TILE;  // <= 512
    const int nblkGa = (N + 15) / 16;

    // workspace carve-up (256B aligned); total ~35.8MB (known-good <= 45.2MB)
    char* w = (char*)d_ws;
    size_t off = 0;
    auto alloc = [&](size_t bytes) -> void* {
        void* p = w + off;
        off += (bytes + 255) & ~(size_t)255;
        return p;
    };
    int*            cursor    = (int*)alloc((size_t)nfine * 16 * 4);
    float*          dinv      = (float*)alloc((size_t)N * 4);
    int*            rowptr    = (int*)alloc(((size_t)N + 1) * 4);
    int*            gstart    = (int*)alloc((NG + 1) * 4);
    int*            srow      = (int*)alloc((size_t)E * 4);
    float*          psum      = (float*)alloc((size_t)nblkGa * HF * 4);
    float*          psq       = (float*)alloc((size_t)nblkGa * HF * 4);
    float*          scale     = (float*)alloc(HF * 4);
    float*          shift     = (float*)alloc(HF * 4);
    unsigned short* A         = (unsigned short*)alloc((size_t)total * 2);  // xw (bf16)
    unsigned short* B         = (unsigned short*)alloc((size_t)total * 2);  // conv out (bf16)
    // buckets (9.6MB) alias B (12.8MB): B dead until gather1 -> gemm1 runs
    // concurrently with bucket_sort (gemm writes A only).
    unsigned*       buckets   = (unsigned*)B;

    const int T256 = 256;
    int gridGemm64 = (N + 63) / 64;
    int nsort      = (E + SORT_CHUNK - 1) / SORT_CHUNK;

    // --- fused CSR-sort || gemm1 (unscaled) ---
    hipMemsetAsync(cursor, 0, (size_t)nfine * 16 * 4, stream);
    sort_gemm1<<<nsort + gridGemm64, T256, 0, stream>>>(row, col, buckets, cursor,
                                                        E, nfine, nsort, x, W1, A, N);
    // CSR place + dinv + gstart + A-row scaling
    tile_place2<<<nfine, T256, 0, stream>>>(buckets, cursor, rowptr, dinv, srow, A,
                                            batch, gstart, N, NG, nfine);

    // --- conv1 gather (+stats) ---
    gather_conv<<<nblkGa, T256, 0, stream>>>(rowptr, srow, dinv, A, b1, B, psum, psq, N);
    bn_reduce<<<HF, 256, 0, stream>>>(psum, psq, g1, be1, scale, shift, nblkGa, N);

    // --- conv2 ---
    gemm_rt<<<gridGemm64, T256, 0, stream>>>(B, W2, A, scale, shift, dinv, N);
    gather_conv<<<nblkGa, T256, 0, stream>>>(rowptr, srow, dinv, A, b2, B, psum, psq, N);
    bn_reduce<<<HF, 256, 0, stream>>>(psum, psq, g2, be2, scale, shift, nblkGa, N);

    // --- fused BN2+ReLU + pooling + classifier ---
    pool_classify<<<NG, 256, 0, stream>>>(B, gstart, scale, shift, Wc, bc, out);
}

// Round 18
// 273.862 us; speedup vs baseline: 1.0691x; 1.0276x over previous
//
#include <hip/hip_runtime.h>

#define HF 128       // feature width (F == H == 128)
#define TILE 128     // cols per fine bucket
#define CAP2 6144    // entries per fine bucket (mean ~4096 + slack)
#define NFINE_MAX 512
#define SORT_CHUNK 8192
#define BN_EPS 1e-5f
// fused smem: staged u32[8192] @0 | sbkt u16[8192] @32768 | hist @49152 |
//             lbase @51200 | gbase @53248 | lofs @55296 | s @57344  = 59392B
// gemm64 path uses the first 34816B as xst[128][68] floats.
#define SMEM_BYTES 59392

__device__ __forceinline__ unsigned short f2bf(float f) {
    unsigned u = __float_as_uint(f);
    unsigned rounding = 0x7FFF + ((u >> 16) & 1);  // round-to-nearest-even
    return (unsigned short)((u + rounding) >> 16);
}
__device__ __forceinline__ float bf2f(unsigned short u) {
    return __uint_as_float(((unsigned)u) << 16);
}
__device__ __forceinline__ unsigned packbf(float lo, float hi) {
    return ((unsigned)f2bf(hi) << 16) | (unsigned)f2bf(lo);
}

// ---------- bucket_sort block body: 8192 edges, 512 threads, two-pass ----------
__device__ __forceinline__ void bucket_sort_block(char* smem, int bid,
                                                  const int* __restrict__ row,
                                                  const int* __restrict__ col,
                                                  unsigned* __restrict__ buckets,
                                                  int* __restrict__ cursor,
                                                  int E, int nfine) {
    unsigned* staged = (unsigned*)smem;                      // 32KB
    unsigned short* sbkt = (unsigned short*)(smem + 32768);  // 16KB
    int* hist  = (int*)(smem + 49152);
    int* lbase = (int*)(smem + 51200);
    int* gbase = (int*)(smem + 53248);
    int* lofs  = (int*)(smem + 55296);
    int* s     = (int*)(smem + 57344);
    int t = threadIdx.x;  // 0..511
    hist[t] = 0;
    lofs[t] = 0;
    __syncthreads();
    int e0 = bid * SORT_CHUNK;
    int n = min(SORT_CHUNK, E - e0);
    for (int i = t; i < n; i += 512) {
        int c = col[e0 + i];
        atomicAdd(&hist[c >> 7], 1);
    }
    __syncthreads();
    // Hillis-Steele inclusive scan over 512 buckets (1 elem/thread, 9 rounds)
    s[t] = hist[t];
    __syncthreads();
    for (int o = 1; o < 512; o <<= 1) {
        int v = (t >= o) ? s[t - o] : 0;
        __syncthreads();
        s[t] += v;
        __syncthreads();
    }
    lbase[t] = s[t] - hist[t];  // exclusive
    {
        int cnt = hist[t];
        gbase[t] = (t < nfine && cnt) ? atomicAdd(&cursor[t * 16], cnt) : 0;
    }
    __syncthreads();
    for (int i = t; i < n; i += 512) {
        int c = col[e0 + i];
        int r = row[e0 + i];
        int b = c >> 7;
        int pos = lbase[b] + atomicAdd(&lofs[b], 1);
        staged[pos] = ((unsigned)(c & 127) << 17) | (unsigned)r;
        sbkt[pos] = (unsigned short)b;
    }
    __syncthreads();
    for (int i = t; i < n; i += 512) {
        int b = sbkt[i];
        int pos = gbase[b] + (i - lbase[b]);
        if (pos < CAP2) buckets[(size_t)b * CAP2 + pos] = staged[i];
    }
}

// ---------- gemm block body: 64x128 tile, 512 threads, 4x4/thread (unscaled) ----------
__device__ __forceinline__ void gemm_block64(char* smem, int bid,
                                             const float* __restrict__ X,
                                             const float* __restrict__ W,
                                             unsigned short* __restrict__ Y, int N) {
    float (*xst)[68] = (float(*)[68])smem;  // [128][68], 272B row stride
    int t = threadIdx.x;  // 0..511
    int row0 = bid * 64;
    {
        int f = t & 127;
        for (int r = (t >> 7); r < 64; r += 4) {
            int rr = row0 + r;
            xst[f][r] = (rr < N) ? X[(size_t)rr * HF + f] : 0.0f;
        }
    }
    __syncthreads();
    int cg = t & 31;   // cols 4*cg..+3
    int rg = t >> 5;   // rows rg*4..+3 (0..15)
    int r0 = rg * 4;
    float acc[4][4] = {};
    const float4* Wv = reinterpret_cast<const float4*>(W);
    #pragma unroll 4
    for (int f = 0; f < HF; ++f) {
        float4 w = Wv[f * 32 + cg];
        float4 xv = *reinterpret_cast<const float4*>(&xst[f][r0]);
        float xr[4] = {xv.x, xv.y, xv.z, xv.w};
        #pragma unroll
        for (int i = 0; i < 4; ++i) {
            acc[i][0] += xr[i] * w.x;
            acc[i][1] += xr[i] * w.y;
            acc[i][2] += xr[i] * w.z;
            acc[i][3] += xr[i] * w.w;
        }
    }
    #pragma unroll
    for (int i = 0; i < 4; ++i) {
        int rr = row0 + r0 + i;
        if (rr < N) {
            ushort4 o;
            o.x = f2bf(acc[i][0]);
            o.y = f2bf(acc[i][1]);
            o.z = f2bf(acc[i][2]);
            o.w = f2bf(acc[i][3]);
            *reinterpret_cast<ushort4*>(&Y[(size_t)rr * HF + cg * 4]) = o;
        }
    }
}

// ---------- fused: bucket_sort (blocks < nsort) || gemm1 UNSCALED (rest) ----------
// Legal: buckets alias B (dead until gather1) while gemm writes A. dinv not yet
// known -> gemm writes unscaled xw; tile_place2 scales A afterward.
__global__ __launch_bounds__(512) void sort_gemm1(const int* __restrict__ row,
                                                  const int* __restrict__ col,
                                                  unsigned* __restrict__ buckets,
                                                  int* __restrict__ cursor,
                                                  int E, int nfine, int nsort,
                                                  const float* __restrict__ x,
                                                  const float* __restrict__ W1,
                                                  unsigned short* __restrict__ A,
                                                  int N) {
    __shared__ __align__(16) char smem[SMEM_BYTES];
    if (blockIdx.x < nsort)
        bucket_sort_block(smem, blockIdx.x, row, col, buckets, cursor, E, nfine);
    else
        gemm_block64(smem, blockIdx.x - nsort, x, W1, A, N);
}

// ---------- standalone gemm (conv2): 64x128 tile, BN1+ReLU on bf16 in, dinv rowscale ----------
__global__ __launch_bounds__(256) void gemm_rt(const unsigned short* __restrict__ Xh,
                                               const float* __restrict__ W,
                                               unsigned short* __restrict__ Y,
                                               const float* __restrict__ scale,
                                               const float* __restrict__ shift,
                                               const float* __restrict__ rowscale,
                                               int N) {
    __shared__ float xst[HF][68];  // 34816B
    int t = threadIdx.x;
    int row0 = blockIdx.x * 64;
    {
        int f = t & 127;
        float sc = scale[f];
        float sh = shift[f];
        for (int r = (t >> 7); r < 64; r += 2) {
            int rr = row0 + r;
            float v = 0.0f;
            if (rr < N) {
                v = bf2f(Xh[(size_t)rr * HF + f]);
                v = fmaxf(v * sc + sh, 0.0f);
            }
            xst[f][r] = v;
        }
    }
    __syncthreads();
    int cg = t & 31;
    int rg = t >> 5;
    int r0 = rg * 8;
    float acc[8][4] = {};
    const float4* Wv = reinterpret_cast<const float4*>(W);
    #pragma unroll 2
    for (int f = 0; f < HF; ++f) {
        float4 w = Wv[f * 32 + cg];
        float4 x0 = *reinterpret_cast<const float4*>(&xst[f][r0]);
        float4 x1 = *reinterpret_cast<const float4*>(&xst[f][r0 + 4]);
        float xr[8] = {x0.x, x0.y, x0.z, x0.w, x1.x, x1.y, x1.z, x1.w};
        #pragma unroll
        for (int i = 0; i < 8; ++i) {
            acc[i][0] += xr[i] * w.x;
            acc[i][1] += xr[i] * w.y;
            acc[i][2] += xr[i] * w.z;
            acc[i][3] += xr[i] * w.w;
        }
    }
    #pragma unroll
    for (int i = 0; i < 8; ++i) {
        int rr = row0 + r0 + i;
        if (rr < N) {
            float rs = rowscale[rr];
            ushort4 o;
            o.x = f2bf(acc[i][0] * rs);
            o.y = f2bf(acc[i][1] * rs);
            o.z = f2bf(acc[i][2] * rs);
            o.w = f2bf(acc[i][3] * rs);
            *reinterpret_cast<ushort4*>(&Y[(size_t)rr * HF + cg * 4]) = o;
        }
    }
}

// ---------- fused per-bucket CSR place + A-row scaling (+graph_bounds, +rowptr[N]) ----------
__global__ __launch_bounds__(256) void tile_place2(const unsigned* __restrict__ buckets,
                                                   const int* __restrict__ cursor,
                                                   int* __restrict__ rowptr,
                                                   float* __restrict__ dinv,
                                                   int* __restrict__ srow,
                                                   unsigned short* __restrict__ A,
                                                   const int* __restrict__ batch,
                                                   int* __restrict__ gstart,
                                                   int N, int NG, int nfine) {
    int b = blockIdx.x;
    int t = threadIdx.x;
    if (b < 2 && t < 129) {
        int g = b * 129 + t;
        if (g <= NG) {
            int lo = 0, hi = N;
            while (lo < hi) {
                int mid = (lo + hi) >> 1;
                if (batch[mid] < g) lo = mid + 1; else hi = mid;
            }
            gstart[g] = lo;
        }
    }
    __shared__ int h[TILE], loc[TILE], cur[TILE];
    __shared__ float dloc[TILE];
    __shared__ int red[256];
    __shared__ int stage[CAP2];
    int part = 0;
    for (int i = t; i < b; i += 256) part += min(cursor[i * 16], CAP2);
    red[t] = part;
    if (t < TILE) h[t] = 0;
    __syncthreads();
    for (int o = 128; o > 0; o >>= 1) {
        if (t < o) red[t] += red[t + o];
        __syncthreads();
    }
    int base = red[0];
    int sz = min(cursor[b * 16], CAP2);
    const unsigned* bk = buckets + (size_t)b * CAP2;
    for (int i = t; i < sz; i += 256) atomicAdd(&h[bk[i] >> 17], 1);
    __syncthreads();
    if (t < TILE) loc[t] = h[t];
    __syncthreads();
    for (int o = 1; o < TILE; o <<= 1) {
        int v = (t < TILE && t >= o) ? loc[t - o] : 0;
        __syncthreads();
        if (t < TILE) loc[t] += v;
        __syncthreads();
    }
    int c0 = b * TILE;
    int ncols = min(TILE, N - c0);
    if (t < TILE) {
        int c = c0 + t;
        int excl = loc[t] - h[t];
        float dc = rsqrtf((float)h[t] + 1.0f);
        if (c < N) {
            rowptr[c] = base + excl;
            dinv[c] = dc;
        }
        dloc[t] = dc;
        cur[t] = excl;
    }
    if (b == nfine - 1 && t == 0) rowptr[N] = base + sz;
    __syncthreads();
    for (int i = t; i < sz; i += 256) {
        unsigned p = bk[i];
        int pos = atomicAdd(&cur[p >> 17], 1);
        if (pos < CAP2) stage[pos] = (int)(p & 0x1FFFFu);
    }
    __syncthreads();
    for (int i = t; i < sz; i += 256) srow[base + i] = stage[i];
    // fold of scale_rows: scale this block's 128 A-rows by dinv (bf16 in-place)
    const unsigned M = 0xffff0000u;
    for (int i = t; i < ncols * 16; i += 256) {
        int nl = i >> 4, j = i & 15;
        float dc = dloc[nl];
        unsigned short* ap = A + (size_t)(c0 + nl) * HF + j * 8;
        uint4 u = *reinterpret_cast<const uint4*>(ap);
        uint4 o;
        o.x = packbf(__uint_as_float(u.x << 16) * dc, __uint_as_float(u.x & M) * dc);
        o.y = packbf(__uint_as_float(u.y << 16) * dc, __uint_as_float(u.y & M) * dc);
        o.z = packbf(__uint_as_float(u.z << 16) * dc, __uint_as_float(u.z & M) * dc);
        o.w = packbf(__uint_as_float(u.w << 16) * dc, __uint_as_float(u.w & M) * dc);
        *reinterpret_cast<uint4*>(ap) = o;
    }
}

// ---------- gather-side conv (bf16 out) + fused BN partial stats ----------
__global__ __launch_bounds__(256) void gather_conv(const int* __restrict__ rowptr,
                                                   const int* __restrict__ srow,
                                                   const float* __restrict__ dinv,
                                                   const unsigned short* __restrict__ XW,
                                                   const float* __restrict__ b,
                                                   unsigned short* __restrict__ OUT,
                                                   float* __restrict__ psum,
                                                   float* __restrict__ psq, int N) {
    int blk = blockIdx.x;
    int c = blk * 16 + (threadIdx.x >> 4);
    int j = threadIdx.x & 15;  // 8 features per lane
    bool valid = (c < N);
    const unsigned M = 0xffff0000u;
    float o[8];
    if (valid) {
        int e = rowptr[c], end = rowptr[c + 1];
        float acc[8] = {0.f, 0.f, 0.f, 0.f, 0.f, 0.f, 0.f, 0.f};
        for (; e + 3 < end; e += 4) {
            int r0 = srow[e], r1 = srow[e + 1], r2 = srow[e + 2], r3 = srow[e + 3];
            uint4 u0 = *reinterpret_cast<const uint4*>(XW + (size_t)r0 * HF + j * 8);
            uint4 u1 = *reinterpret_cast<const uint4*>(XW + (size_t)r1 * HF + j * 8);
            uint4 u2 = *reinterpret_cast<const uint4*>(XW + (size_t)r2 * HF + j * 8);
            uint4 u3 = *reinterpret_cast<const uint4*>(XW + (size_t)r3 * HF + j * 8);
            acc[0] += (__uint_as_float(u0.x << 16) + __uint_as_float(u1.x << 16))
                    + (__uint_as_float(u2.x << 16) + __uint_as_float(u3.x << 16));
            acc[1] += (__uint_as_float(u0.x & M) + __uint_as_float(u1.x & M))
                    + (__uint_as_float(u2.x & M) + __uint_as_float(u3.x & M));
            acc[2] += (__uint_as_float(u0.y << 16) + __uint_as_float(u1.y << 16))
                    + (__uint_as_float(u2.y << 16) + __uint_as_float(u3.y << 16));
            acc[3] += (__uint_as_float(u0.y & M) + __uint_as_float(u1.y & M))
                    + (__uint_as_float(u2.y & M) + __uint_as_float(u3.y & M));
            acc[4] += (__uint_as_float(u0.z << 16) + __uint_as_float(u1.z << 16))
                    + (__uint_as_float(u2.z << 16) + __uint_as_float(u3.z << 16));
            acc[5] += (__uint_as_float(u0.z & M) + __uint_as_float(u1.z & M))
                    + (__uint_as_float(u2.z & M) + __uint_as_float(u3.z & M));
            acc[6] += (__uint_as_float(u0.w << 16) + __uint_as_float(u1.w << 16))
                    + (__uint_as_float(u2.w << 16) + __uint_as_float(u3.w << 16));
            acc[7] += (__uint_as_float(u0.w & M) + __uint_as_float(u1.w & M))
                    + (__uint_as_float(u2.w & M) + __uint_as_float(u3.w & M));
        }
        for (; e < end; ++e) {
            int r0 = srow[e];
            uint4 u0 = *reinterpret_cast<const uint4*>(XW + (size_t)r0 * HF + j * 8);
            acc[0] += __uint_as_float(u0.x << 16);
            acc[1] += __uint_as_float(u0.x & M);
            acc[2] += __uint_as_float(u0.y << 16);
            acc[3] += __uint_as_float(u0.y & M);
            acc[4] += __uint_as_float(u0.z << 16);
            acc[5] += __uint_as_float(u0.z & M);
            acc[6] += __uint_as_float(u0.w << 16);
            acc[7] += __uint_as_float(u0.w & M);
        }
        float dc = dinv[c];
        uint4 xv = *reinterpret_cast<const uint4*>(XW + (size_t)c * HF + j * 8);
        acc[0] += __uint_as_float(xv.x << 16);
        acc[1] += __uint_as_float(xv.x & M);
        acc[2] += __uint_as_float(xv.y << 16);
        acc[3] += __uint_as_float(xv.y & M);
        acc[4] += __uint_as_float(xv.z << 16);
        acc[5] += __uint_as_float(xv.z & M);
        acc[6] += __uint_as_float(xv.w << 16);
        acc[7] += __uint_as_float(xv.w & M);
        float4 b0 = *reinterpret_cast<const float4*>(b + j * 8);
        float4 b1 = *reinterpret_cast<const float4*>(b + j * 8 + 4);
        o[0] = dc * acc[0] + b0.x;
        o[1] = dc * acc[1] + b0.y;
        o[2] = dc * acc[2] + b0.z;
        o[3] = dc * acc[3] + b0.w;
        o[4] = dc * acc[4] + b1.x;
        o[5] = dc * acc[5] + b1.y;
        o[6] = dc * acc[6] + b1.z;
        o[7] = dc * acc[7] + b1.w;
        uint4 ov;
        ov.x = packbf(o[0], o[1]);
        ov.y = packbf(o[2], o[3]);
        ov.z = packbf(o[4], o[5]);
        ov.w = packbf(o[6], o[7]);
        *reinterpret_cast<uint4*>(OUT + (size_t)c * HF + j * 8) = ov;
    } else {
        #pragma unroll
        for (int k = 0; k < 8; ++k) o[k] = 0.f;
    }
    __shared__ float sval[16][HF + 4];
    int r = threadIdx.x >> 4;
    *reinterpret_cast<float4*>(&sval[r][j * 8]) = make_float4(o[0], o[1], o[2], o[3]);
    *reinterpret_cast<float4*>(&sval[r][j * 8 + 4]) = make_float4(o[4], o[5], o[6], o[7]);
    __syncthreads();
    if (threadIdx.x < HF) {
        float s = 0.f, sq = 0.f;
        #pragma unroll
        for (int rr = 0; rr < 16; ++rr) {
            float v = sval[rr][threadIdx.x];
            s += v;
            sq += v * v;
        }
        psum[(size_t)blk * HF + threadIdx.x] = s;
        psq[(size_t)blk * HF + threadIdx.x] = sq;
    }
}

// ---------- BN reduce (partials -> scale/shift) ----------
__global__ __launch_bounds__(256) void bn_reduce(const float* __restrict__ psum,
                                                 const float* __restrict__ psq,
                                                 const float* __restrict__ gamma,
                                                 const float* __restrict__ beta,
                                                 float* __restrict__ scale,
                                                 float* __restrict__ shift,
                                                 int nblk, int N) {
    int f = blockIdx.x;
    int t = threadIdx.x;
    float s = 0.f, sq = 0.f;
    for (int i = t; i < nblk; i += 256) {
        s += psum[(size_t)i * HF + f];
        sq += psq[(size_t)i * HF + f];
    }
    __shared__ float ls[256], lq[256];
    ls[t] = s; lq[t] = sq;
    __syncthreads();
    for (int o = 128; o > 0; o >>= 1) {
        if (t < o) { ls[t] += ls[t + o]; lq[t] += lq[t + o]; }
        __syncthreads();
    }
    if (t == 0) {
        float invn = 1.0f / (float)N;
        float mu = ls[0] * invn;
        float var = lq[0] * invn - mu * mu;
        float sc = gamma[f] * rsqrtf(var + BN_EPS);
        scale[f] = sc;
        shift[f] = beta[f] - mu * sc;
    }
}

// ---------- fused BN2+ReLU + mean/max/sum pool + classifier (bf16 B) ----------
__global__ __launch_bounds__(256) void pool_classify(const unsigned short* __restrict__ Bh,
                                                     const int* __restrict__ gstart,
                                                     const float* __restrict__ scale,
                                                     const float* __restrict__ shift,
                                                     const float* __restrict__ Wc,
                                                     const float* __restrict__ bc,
                                                     float* __restrict__ out) {
    int g = blockIdx.x;
    int t = threadIdx.x & 127;
    int half = threadIdx.x >> 7;
    int s0 = gstart[g], s1 = gstart[g + 1];
    float sc = scale[t], sh = shift[t];
    float sum = 0.f, mx = 0.f;  // 0-init == empty-graph guard
    for (int n = s0 + half; n < s1; n += 2) {
        float v = fmaxf(bf2f(Bh[(size_t)n * HF + t]) * sc + sh, 0.0f);
        sum += v;
        mx = fmaxf(mx, v);
    }
    __shared__ float shsum[2][HF], shmax[2][HF];
    __shared__ float red[3][HF];
    shsum[half][t] = sum;
    shmax[half][t] = mx;
    __syncthreads();
    if (half == 0) {
        sum += shsum[1][t];
        mx = fmaxf(mx, shmax[1][t]);
        float cntf = (float)(s1 - s0);
        float mean = sum / fmaxf(cntf, 1.0f);
        red[0][t] = mean * Wc[t * 3 + 0] + mx * Wc[(HF + t) * 3 + 0] + sum * Wc[(2 * HF + t) * 3 + 0];
        red[1][t] = mean * Wc[t * 3 + 1] + mx * Wc[(HF + t) * 3 + 1] + sum * Wc[(2 * HF + t) * 3 + 1];
        red[2][t] = mean * Wc[t * 3 + 2] + mx * Wc[(HF + t) * 3 + 2] + sum * Wc[(2 * HF + t) * 3 + 2];
    }
    __syncthreads();
    for (int o = 64; o > 0; o >>= 1) {
        if (half == 0 && t < o) {
            red[0][t] += red[0][t + o];
            red[1][t] += red[1][t + o];
            red[2][t] += red[2][t + o];
        }
        __syncthreads();
    }
    if (threadIdx.x < 3) out[g * 3 + threadIdx.x] = red[threadIdx.x][0] + bc[threadIdx.x];
}

extern "C" void kernel_launch(void* const* d_in, const int* in_sizes, int n_in,
                              void* d_out, int out_size, void* d_ws, size_t ws_size,
                              hipStream_t stream) {
    const float* x    = (const float*)d_in[0];
    const int*   ei   = (const int*)d_in[1];
    const int*   batch= (const int*)d_in[2];
    const float* W1   = (const float*)d_in[3];
    const float* b1   = (const float*)d_in[4];
    const float* g1   = (const float*)d_in[5];
    const float* be1  = (const float*)d_in[6];
    const float* W2   = (const float*)d_in[7];
    const float* b2   = (const float*)d_in[8];
    const float* g2   = (const float*)d_in[9];
    const float* be2  = (const float*)d_in[10];
    const float* Wc   = (const float*)d_in[11];
    const float* bc   = (const float*)d_in[12];
    float* out = (float*)d_out;

    const int N = in_sizes[0] / HF;
    const int E = in_sizes[1] / 2;
    const int NG = 256;
    const int* row = ei;
    const int* col = ei + E;
    const int total = N * HF;
    const int nfine = (N + TILE - 1) / TILE;  // <= 512
    const int nblkGa = (N + 15) / 16;

    // workspace carve-up (256B aligned); total ~35.8MB (known-good <= 45.2MB)
    char* w = (char*)d_ws;
    size_t off = 0;
    auto alloc = [&](size_t bytes) -> void* {
        void* p = w + off;
        off += (bytes + 255) & ~(size_t)255;
        return p;
    };
    int*            cursor    = (int*)alloc((size_t)nfine * 16 * 4);
    float*          dinv      = (float*)alloc((size_t)N * 4);
    int*            rowptr    = (int*)alloc(((size_t)N + 1) * 4);
    int*            gstart    = (int*)alloc((NG + 1) * 4);
    int*            srow      = (int*)alloc((size_t)E * 4);
    float*          psum      = (float*)alloc((size_t)nblkGa * HF * 4);
    float*          psq       = (float*)alloc((size_t)nblkGa * HF * 4);
    float*          scale     = (float*)alloc(HF * 4);
    float*          shift     = (float*)alloc(HF * 4);
    unsigned short* A         = (unsigned short*)alloc((size_t)total * 2);  // xw (bf16)
    unsigned short* B         = (unsigned short*)alloc((size_t)total * 2);  // conv out (bf16)
    // buckets (9.6MB) alias B (12.8MB): B dead until gather1 -> gemm1 runs
    // concurrently with bucket_sort (gemm writes A only).
    unsigned*       buckets   = (unsigned*)B;

    int gridGemm64 = (N + 63) / 64;
    int nsort      = (E + SORT_CHUNK - 1) / SORT_CHUNK;

    // --- fused CSR-sort || gemm1 (unscaled), 512 threads ---
    hipMemsetAsync(cursor, 0, (size_t)nfine * 16 * 4, stream);
    sort_gemm1<<<nsort + gridGemm64, 512, 0, stream>>>(row, col, buckets, cursor,
                                                       E, nfine, nsort, x, W1, A, N);
    // CSR place + dinv + gstart + A-row scaling
    tile_place2<<<nfine, 256, 0, stream>>>(buckets, cursor, rowptr, dinv, srow, A,
                                           batch, gstart, N, NG, nfine);

    // --- conv1 gather (+stats) ---
    gather_conv<<<nblkGa, 256, 0, stream>>>(rowptr, srow, dinv, A, b1, B, psum, psq, N);
    bn_reduce<<<HF, 256, 0, stream>>>(psum, psq, g1, be1, scale, shift, nblkGa, N);

    // --- conv2 ---
    gemm_rt<<<gridGemm64, 256, 0, stream>>>(B, W2, A, scale, shift, dinv, N);
    gather_conv<<<nblkGa, 256, 0, stream>>>(rowptr, srow, dinv, A, b2, B, psum, psq, N);
    bn_reduce<<<HF, 256, 0, stream>>>(psum, psq, g2, be2, scale, shift, nblkGa, N);

    // --- fused BN2+ReLU + pooling + classifier ---
    pool_classify<<<NG, 256, 0, stream>>>(B, gstart, scale, shift, Wc, bc, out);
}